// Round 3
// baseline (921.821 us; speedup 1.0000x reference)
//
#include <hip/hip_runtime.h>
#include <hip/hip_bf16.h>

// Problem constants (from reference setup_inputs)
#define N0 200000
#define N1 50000
#define N2 10000
#define E1C 800000
#define E2C 160000
// IN_F=128, HID=128, RANK=64, OUT_C=64

// ---------------------------------------------------------------------------
__global__ void zero_ints(int* __restrict__ a, int n) {
    int i = blockIdx.x * blockDim.x + threadIdx.x;
    if (i < n) a[i] = 0;
}

// fused histogram of both layers' dst indices
__global__ void hist_dual(const int* __restrict__ d1, int* __restrict__ c1, int e1,
                          const int* __restrict__ d2, int* __restrict__ c2, int e2) {
    int i = blockIdx.x * blockDim.x + threadIdx.x;
    if (i < e1) {
        atomicAdd(&c1[d1[i]], 1);
    } else {
        int j = i - e1;
        if (j < e2) atomicAdd(&c2[d2[j]], 1);
    }
}

// ---------------------------------------------------------------------------
// 3-phase exclusive scan (block chunk = 1024 elements, 256 threads x int4)

__global__ __launch_bounds__(256) void scan_partial_dual(
    const int* __restrict__ c1, int n1, int* __restrict__ p1, int B1,
    const int* __restrict__ c2, int n2, int* __restrict__ p2) {
    const int* c; int n; int* p; int b;
    if ((int)blockIdx.x < B1) { c = c1; n = n1; p = p1; b = blockIdx.x; }
    else { c = c2; n = n2; p = p2; b = blockIdx.x - B1; }
    int base = b * 1024 + threadIdx.x * 4;
    int s = 0;
    if (base < n) {  // n % 4 == 0 for both layers -> full int4 in-bounds
        int4 v = *reinterpret_cast<const int4*>(c + base);
        s = v.x + v.y + v.z + v.w;
    }
    #pragma unroll
    for (int o = 32; o > 0; o >>= 1) s += __shfl_xor(s, o, 64);
    __shared__ int ws[4];
    if ((threadIdx.x & 63) == 0) ws[threadIdx.x >> 6] = s;
    __syncthreads();
    if (threadIdx.x == 0) p[b] = ws[0] + ws[1] + ws[2] + ws[3];
}

// phase 2: single wave scans both partial arrays (lens <= 64)
__global__ void scan_mid(int* __restrict__ p1, int n1, int* __restrict__ p2, int n2) {
    int lane = threadIdx.x;
    int v = (lane < n1) ? p1[lane] : 0;
    int s = v;
    #pragma unroll
    for (int o = 1; o < 64; o <<= 1) { int t = __shfl_up(s, o, 64); if (lane >= o) s += t; }
    if (lane < n1) p1[lane] = s - v;
    int v2 = (lane < n2) ? p2[lane] : 0;
    int s2 = v2;
    #pragma unroll
    for (int o = 1; o < 64; o <<= 1) { int t = __shfl_up(s2, o, 64); if (lane >= o) s2 += t; }
    if (lane < n2) p2[lane] = s2 - v2;
}

// phase 3: per-element exclusive scan; writes offs[] and cursor[] (cursor aliases cnt)
__global__ __launch_bounds__(256) void scan_final_dual(
    int* __restrict__ c1, int* __restrict__ offs1, int n1, int e1, const int* __restrict__ p1, int B1,
    int* __restrict__ c2, int* __restrict__ offs2, int n2, int e2, const int* __restrict__ p2) {
    int* c; int* offs; int n; int e; const int* p; int b;
    if ((int)blockIdx.x < B1) { c = c1; offs = offs1; n = n1; e = e1; p = p1; b = blockIdx.x; }
    else { c = c2; offs = offs2; n = n2; e = e2; p = p2; b = blockIdx.x - B1; }
    int tid = threadIdx.x, lane = tid & 63, wid = tid >> 6;
    int base = b * 1024 + tid * 4;
    int4 v = make_int4(0, 0, 0, 0);
    if (base < n) v = *reinterpret_cast<const int4*>(c + base);
    int s4 = v.x + v.y + v.z + v.w;
    int s = s4;
    #pragma unroll
    for (int o = 1; o < 64; o <<= 1) { int t = __shfl_up(s, o, 64); if (lane >= o) s += t; }
    __shared__ int wsum[4];
    if (lane == 63) wsum[wid] = s;
    __syncthreads();
    int wbase = 0;
    #pragma unroll
    for (int w = 0; w < 4; ++w) if (w < wid) wbase += wsum[w];
    int excl = p[b] + wbase + (s - s4);
    if (base < n) {
        int o0 = excl, o1 = o0 + v.x, o2 = o1 + v.y, o3 = o2 + v.z;
        int4 ov = make_int4(o0, o1, o2, o3);
        *reinterpret_cast<int4*>(offs + base) = ov;
        *reinterpret_cast<int4*>(c + base) = ov;  // cursor
    }
    if (b == 0 && tid == 0) offs[n] = e;
}

// fused scatter for both layers: sorted[pos] = src[e]
__global__ void scatter_dual(const int* __restrict__ d1, const int* __restrict__ s1,
                             int* __restrict__ cur1, int* __restrict__ so1, int e1,
                             const int* __restrict__ d2, const int* __restrict__ s2,
                             int* __restrict__ cur2, int* __restrict__ so2, int e2) {
    int i = blockIdx.x * blockDim.x + threadIdx.x;
    if (i < e1) {
        int p = atomicAdd(&cur1[d1[i]], 1);
        so1[p] = s1[i];
    } else {
        int j = i - e1;
        if (j < e2) {
            int p = atomicAdd(&cur2[d2[j]], 1);
            so2[p] = s2[j];
        }
    }
}

// ---------------------------------------------------------------------------
// Column-stationary GEMM: lane = output column, W col-slice lives in VGPRs
// (K * NCHUNK regs, loaded once per wave), A rows stream through SGPRs via
// wave-uniform s_loads (row pointer forced uniform with readfirstlane).
// Inner loop is pure v_fmac_f32 acc, s_a, v_w.
// out[M x NCHUNK*64] = A[M x K] @ W[K x NCHUNK*64] (+bias) (+relu)
#define RPW 64  // rows per wave

template <int K, int NCHUNK, bool RELU, bool BIAS>
__device__ __forceinline__ void colmm_body(const float* __restrict__ A,
                                           const float* __restrict__ W,
                                           const float* __restrict__ bias,
                                           float* __restrict__ out,
                                           int M, int wv, int lane) {
    const int NT = NCHUNK * 64;
    int r0 = wv * RPW;
    if (r0 >= M) return;
    // preload W column slice into VGPRs (coalesced; W is L2-hot)
    float wreg[NCHUNK][K];
    #pragma unroll
    for (int c = 0; c < NCHUNK; ++c)
        #pragma unroll
        for (int k = 0; k < K; ++k)
            wreg[c][k] = W[(size_t)k * NT + c * 64 + lane];
    float bz[NCHUNK];
    #pragma unroll
    for (int c = 0; c < NCHUNK; ++c) bz[c] = BIAS ? bias[c * 64 + lane] : 0.0f;

    int rend = r0 + RPW; if (rend > M) rend = M;
    for (int r = r0; r < rend; r += 4) {
        const float* Ap[4];
        #pragma unroll
        for (int g = 0; g < 4; ++g) {
            int rr = r + g; if (rr >= M) rr = M - 1;
            Ap[g] = A + (size_t)__builtin_amdgcn_readfirstlane(rr) * K;
        }
        float acc[4][NCHUNK];
        #pragma unroll
        for (int g = 0; g < 4; ++g)
            #pragma unroll
            for (int c = 0; c < NCHUNK; ++c) acc[g][c] = 0.0f;
        #pragma unroll
        for (int k = 0; k < K; ++k) {
            #pragma unroll
            for (int g = 0; g < 4; ++g) {
                float a = Ap[g][k];  // wave-uniform -> s_load
                #pragma unroll
                for (int c = 0; c < NCHUNK; ++c)
                    acc[g][c] = fmaf(a, wreg[c][k], acc[g][c]);
            }
        }
        #pragma unroll
        for (int g = 0; g < 4; ++g) {
            int rr = r + g;
            if (rr < M) {
                #pragma unroll
                for (int c = 0; c < NCHUNK; ++c) {
                    float v = acc[g][c] + bz[c];
                    if (RELU) v = fmaxf(v, 0.0f);
                    out[(size_t)rr * NT + c * 64 + lane] = v;
                }
            }
        }
    }
}

template <int K, int NCHUNK, bool RELU, bool BIAS>
__global__ __launch_bounds__(256, 3) void colmm(const float* __restrict__ A,
                                                const float* __restrict__ W,
                                                const float* __restrict__ bias,
                                                float* __restrict__ out, int M) {
    int lane = threadIdx.x & 63;
    int wv = blockIdx.x * 4 + (threadIdx.x >> 6);
    colmm_body<K, NCHUNK, RELU, BIAS>(A, W, bias, out, M, wv, lane);
}

// two independent K=128 N=64 GEMMs (same or different A), split by wave id
template <int K>
__global__ __launch_bounds__(256, 3) void colmm_dual(const float* __restrict__ A,
                                                     const float* __restrict__ Wa,
                                                     float* __restrict__ outa, int Ma, int WavesA,
                                                     const float* __restrict__ Wb,
                                                     float* __restrict__ outb, int Mb) {
    int lane = threadIdx.x & 63;
    int wv = blockIdx.x * 4 + (threadIdx.x >> 6);
    if (wv < WavesA) {
        colmm_body<K, 1, false, false>(A, Wa, nullptr, outa, Ma, wv, lane);
    } else {
        colmm_body<K, 1, false, false>(A, Wb, nullptr, outb, Mb, wv - WavesA, lane);
    }
}

// ---------------------------------------------------------------------------
// One wave per dst node. lane = (edge_slot = lane>>4, float4_chunk = lane&15).
// z (in-place) = mean(hsrc[src]) * z
__global__ __launch_bounds__(256) void agg_mul(const float* __restrict__ hsrc,
                                               const int* __restrict__ offs,
                                               const int* __restrict__ sorted,
                                               float* __restrict__ z, int ndst) {
    int wid = threadIdx.x >> 6;
    int lane = threadIdx.x & 63;
    int d = blockIdx.x * 4 + wid;
    if (d >= ndst) return;
    int start = offs[d];
    int end = offs[d + 1];
    int sub = lane >> 4;
    int fq = lane & 15;
    float4 acc = make_float4(0.f, 0.f, 0.f, 0.f);
    for (int e = start + sub; e < end; e += 4) {
        int sidx = sorted[e];
        float4 v = *reinterpret_cast<const float4*>(hsrc + (size_t)sidx * 64 + fq * 4);
        acc.x += v.x; acc.y += v.y; acc.z += v.z; acc.w += v.w;
    }
    #pragma unroll
    for (int o = 16; o <= 32; o <<= 1) {
        acc.x += __shfl_xor(acc.x, o, 64);
        acc.y += __shfl_xor(acc.y, o, 64);
        acc.z += __shfl_xor(acc.z, o, 64);
        acc.w += __shfl_xor(acc.w, o, 64);
    }
    if (sub == 0) {
        int cnt = end - start;
        float inv = (cnt > 0) ? (1.0f / (float)cnt) : 0.0f;
        size_t idx = (size_t)d * 64 + fq * 4;
        float4 hd = *reinterpret_cast<const float4*>(z + idx);
        float4 r;
        r.x = acc.x * inv * hd.x; r.y = acc.y * inv * hd.y;
        r.z = acc.z * inv * hd.z; r.w = acc.w * inv * hd.w;
        *reinterpret_cast<float4*>(z + idx) = r;
    }
}

// ---------------------------------------------------------------------------
extern "C" void kernel_launch(void* const* d_in, const int* in_sizes, int n_in,
                              void* d_out, int out_size, void* d_ws, size_t ws_size,
                              hipStream_t stream) {
    const float* x     = (const float*)d_in[0];
    const float* Wsrc1 = (const float*)d_in[1];
    const float* Wdst1 = (const float*)d_in[2];
    const float* Wout1 = (const float*)d_in[3];
    const float* b1    = (const float*)d_in[4];
    const float* Wsrc2 = (const float*)d_in[5];
    const float* Wdst2 = (const float*)d_in[6];
    const float* Wout2 = (const float*)d_in[7];
    const float* b2    = (const float*)d_in[8];
    const int* src1    = (const int*)d_in[9];
    const int* dst1    = (const int*)d_in[10];
    const int* src2    = (const int*)d_in[11];
    const int* dst2    = (const int*)d_in[12];
    float* out = (float*)d_out;

    // workspace layout
    float* f = (float*)d_ws;
    float* hsrc1 = f;                          // N0*64 (reused as hsrc2)
    float* hdst1 = hsrc1 + (size_t)N0 * 64;    // N1*64 (becomes z1 in-place)
    float* h     = hdst1 + (size_t)N1 * 64;    // N1*128
    float* hdst2 = h + (size_t)N1 * 128;       // N2*64 (becomes z2 in-place)
    int* ip = (int*)(hdst2 + (size_t)N2 * 64);
    int* cur1    = ip; ip += N1;               // cur1,cur2 contiguous for fused zero
    int* cur2    = ip; ip += N2;
    int* offs1   = ip; ip += N1 + 4;
    int* offs2   = ip; ip += N2 + 4;
    int* sorted1 = ip; ip += E1C;
    int* sorted2 = ip; ip += E2C;
    int* part1   = ip; ip += 52;
    int* part2   = ip; ip += 12;

    const int B1 = (N1 + 1023) / 1024;   // 49
    const int B2 = (N2 + 1023) / 1024;   // 10

    // --- CSR build for both layers ---
    zero_ints<<<(N1 + N2 + 255) / 256, 256, 0, stream>>>(cur1, N1 + N2);
    hist_dual<<<(E1C + E2C + 255) / 256, 256, 0, stream>>>(dst1, cur1, E1C, dst2, cur2, E2C);
    scan_partial_dual<<<B1 + B2, 256, 0, stream>>>(cur1, N1, part1, B1, cur2, N2, part2);
    scan_mid<<<1, 64, 0, stream>>>(part1, B1, part2, B2);
    scan_final_dual<<<B1 + B2, 256, 0, stream>>>(cur1, offs1, N1, E1C, part1, B1,
                                                 cur2, offs2, N2, E2C, part2);
    scatter_dual<<<(E1C + E2C + 255) / 256, 256, 0, stream>>>(dst1, src1, cur1, sorted1, E1C,
                                                              dst2, src2, cur2, sorted2, E2C);

    // --- layer 1 ---
    {
        int Wa = (N0 + RPW - 1) / RPW, Wb = (N1 + RPW - 1) / RPW;
        int blocks = (Wa + Wb + 3) / 4;
        colmm_dual<128><<<blocks, 256, 0, stream>>>(x, Wsrc1, hsrc1, N0, Wa, Wdst1, hdst1, N1);
    }
    agg_mul<<<(N1 + 3) / 4, 256, 0, stream>>>(hsrc1, offs1, sorted1, hdst1, N1);
    {
        int Wv = (N1 + RPW - 1) / RPW;
        colmm<64, 2, true, true><<<(Wv + 3) / 4, 256, 0, stream>>>(hdst1, Wout1, b1, h, N1);
    }

    // --- layer 2 (hsrc1 buffer reused as hsrc2) ---
    {
        int Wa = (N1 + RPW - 1) / RPW, Wb = (N2 + RPW - 1) / RPW;
        int blocks = (Wa + Wb + 3) / 4;
        colmm_dual<128><<<blocks, 256, 0, stream>>>(h, Wsrc2, hsrc1, N1, Wa, Wdst2, hdst2, N2);
    }
    agg_mul<<<(N2 + 3) / 4, 256, 0, stream>>>(hsrc1, offs2, sorted2, hdst2, N2);
    {
        int Wv = (N2 + RPW - 1) / RPW;
        colmm<64, 1, false, true><<<(Wv + 3) / 4, 256, 0, stream>>>(hdst2, Wout2, b2, out, N2);
    }
}

// Round 4
// 505.018 us; speedup vs baseline: 1.8253x; 1.8253x over previous
//
#include <hip/hip_runtime.h>
#include <hip/hip_bf16.h>

// Problem constants (from reference setup_inputs)
#define N0 200000
#define N1 50000
#define N2 10000
#define E1C 800000
#define E2C 160000
// IN_F=128, HID=128, RANK=64, OUT_C=64

// ---------------------------------------------------------------------------
__global__ void zero_ints(int* __restrict__ a, int n) {
    int i = blockIdx.x * blockDim.x + threadIdx.x;
    if (i < n) a[i] = 0;
}

// fused histogram of both layers' dst indices
__global__ void hist_dual(const int* __restrict__ d1, int* __restrict__ c1, int e1,
                          const int* __restrict__ d2, int* __restrict__ c2, int e2) {
    int i = blockIdx.x * blockDim.x + threadIdx.x;
    if (i < e1) {
        atomicAdd(&c1[d1[i]], 1);
    } else {
        int j = i - e1;
        if (j < e2) atomicAdd(&c2[d2[j]], 1);
    }
}

// ---------------------------------------------------------------------------
// 3-phase exclusive scan (block chunk = 1024 elements, 256 threads x int4)

__global__ __launch_bounds__(256) void scan_partial_dual(
    const int* __restrict__ c1, int n1, int* __restrict__ p1, int B1,
    const int* __restrict__ c2, int n2, int* __restrict__ p2) {
    const int* c; int n; int* p; int b;
    if ((int)blockIdx.x < B1) { c = c1; n = n1; p = p1; b = blockIdx.x; }
    else { c = c2; n = n2; p = p2; b = blockIdx.x - B1; }
    int base = b * 1024 + threadIdx.x * 4;
    int s = 0;
    if (base < n) {  // n % 4 == 0 for both layers -> full int4 in-bounds
        int4 v = *reinterpret_cast<const int4*>(c + base);
        s = v.x + v.y + v.z + v.w;
    }
    #pragma unroll
    for (int o = 32; o > 0; o >>= 1) s += __shfl_xor(s, o, 64);
    __shared__ int ws[4];
    if ((threadIdx.x & 63) == 0) ws[threadIdx.x >> 6] = s;
    __syncthreads();
    if (threadIdx.x == 0) p[b] = ws[0] + ws[1] + ws[2] + ws[3];
}

// phase 2: single wave scans both partial arrays (lens <= 64)
__global__ void scan_mid(int* __restrict__ p1, int n1, int* __restrict__ p2, int n2) {
    int lane = threadIdx.x;
    int v = (lane < n1) ? p1[lane] : 0;
    int s = v;
    #pragma unroll
    for (int o = 1; o < 64; o <<= 1) { int t = __shfl_up(s, o, 64); if (lane >= o) s += t; }
    if (lane < n1) p1[lane] = s - v;
    int v2 = (lane < n2) ? p2[lane] : 0;
    int s2 = v2;
    #pragma unroll
    for (int o = 1; o < 64; o <<= 1) { int t = __shfl_up(s2, o, 64); if (lane >= o) s2 += t; }
    if (lane < n2) p2[lane] = s2 - v2;
}

// phase 3: per-element exclusive scan; writes offs[] and cursor[] (cursor aliases cnt)
__global__ __launch_bounds__(256) void scan_final_dual(
    int* __restrict__ c1, int* __restrict__ offs1, int n1, int e1, const int* __restrict__ p1, int B1,
    int* __restrict__ c2, int* __restrict__ offs2, int n2, int e2, const int* __restrict__ p2) {
    int* c; int* offs; int n; int e; const int* p; int b;
    if ((int)blockIdx.x < B1) { c = c1; offs = offs1; n = n1; e = e1; p = p1; b = blockIdx.x; }
    else { c = c2; offs = offs2; n = n2; e = e2; p = p2; b = blockIdx.x - B1; }
    int tid = threadIdx.x, lane = tid & 63, wid = tid >> 6;
    int base = b * 1024 + tid * 4;
    int4 v = make_int4(0, 0, 0, 0);
    if (base < n) v = *reinterpret_cast<const int4*>(c + base);
    int s4 = v.x + v.y + v.z + v.w;
    int s = s4;
    #pragma unroll
    for (int o = 1; o < 64; o <<= 1) { int t = __shfl_up(s, o, 64); if (lane >= o) s += t; }
    __shared__ int wsum[4];
    if (lane == 63) wsum[wid] = s;
    __syncthreads();
    int wbase = 0;
    #pragma unroll
    for (int w = 0; w < 4; ++w) if (w < wid) wbase += wsum[w];
    int excl = p[b] + wbase + (s - s4);
    if (base < n) {
        int o0 = excl, o1 = o0 + v.x, o2 = o1 + v.y, o3 = o2 + v.z;
        int4 ov = make_int4(o0, o1, o2, o3);
        *reinterpret_cast<int4*>(offs + base) = ov;
        *reinterpret_cast<int4*>(c + base) = ov;  // cursor
    }
    if (b == 0 && tid == 0) offs[n] = e;
}

// fused scatter for both layers: sorted[pos] = src[e]
__global__ void scatter_dual(const int* __restrict__ d1, const int* __restrict__ s1,
                             int* __restrict__ cur1, int* __restrict__ so1, int e1,
                             const int* __restrict__ d2, const int* __restrict__ s2,
                             int* __restrict__ cur2, int* __restrict__ so2, int e2) {
    int i = blockIdx.x * blockDim.x + threadIdx.x;
    if (i < e1) {
        int p = atomicAdd(&cur1[d1[i]], 1);
        so1[p] = s1[i];
    } else {
        int j = i - e1;
        if (j < e2) {
            int p = atomicAdd(&cur2[d2[j]], 1);
            so2[p] = s2[j];
        }
    }
}

// ---------------------------------------------------------------------------
// LDS-tiled register-blocked fp32 GEMM.
// out[M x BN] = A[M x KTOT] @ W[KTOT x BN] (+bias) (+relu), BN == full N.
// Block tile: BM x BN, BK=32. Thread tile: 8x8 (acc[8][8] in VGPRs).
// As stored transposed [k][m] with +4 pad: 16B-aligned rows -> ds_read_b128
// on compute, 4-way (1.58x) conflicts only on the staging scatter writes.
template <int KTOT, int BM, int BN, bool RELU, bool BIAS>
__global__ __launch_bounds__((BM / 8) * (BN / 8), 2)
void gemm_tiled(const float* __restrict__ A, const float* __restrict__ W,
                const float* __restrict__ bias, float* __restrict__ out, int M) {
    constexpr int THREADS = (BM / 8) * (BN / 8);
    __shared__ float As[32][BM + 4];
    __shared__ float Ws[32][BN];
    const int t = threadIdx.x;
    const int tx = t % (BN / 8);   // col group
    const int ty = t / (BN / 8);   // row group
    const int r0 = blockIdx.x * BM;

    float acc[8][8];
    #pragma unroll
    for (int i = 0; i < 8; ++i)
        #pragma unroll
        for (int j = 0; j < 8; ++j) acc[i][j] = 0.0f;

    for (int k0 = 0; k0 < KTOT; k0 += 32) {
        // stage A: BM rows x 32 k, one float4 per (row, kq); write transposed
        #pragma unroll
        for (int f = t; f < BM * 8; f += THREADS) {
            int row = f >> 3, kq = f & 7;
            int gr = r0 + row; if (gr > M - 1) gr = M - 1;
            float4 v = *reinterpret_cast<const float4*>(A + (size_t)gr * KTOT + k0 + kq * 4);
            As[kq * 4 + 0][row] = v.x;
            As[kq * 4 + 1][row] = v.y;
            As[kq * 4 + 2][row] = v.z;
            As[kq * 4 + 3][row] = v.w;
        }
        // stage W: 32 x BN, straight float4 copy
        #pragma unroll
        for (int f = t; f < BN * 8; f += THREADS) {
            int k = f / (BN / 4), nq = f % (BN / 4);
            *reinterpret_cast<float4*>(&Ws[k][nq * 4]) =
                *reinterpret_cast<const float4*>(W + (size_t)(k0 + k) * BN + nq * 4);
        }
        __syncthreads();
        #pragma unroll 4
        for (int k = 0; k < 32; ++k) {
            float a[8], w[8];
            *reinterpret_cast<float4*>(&a[0]) = *reinterpret_cast<const float4*>(&As[k][ty * 8]);
            *reinterpret_cast<float4*>(&a[4]) = *reinterpret_cast<const float4*>(&As[k][ty * 8 + 4]);
            *reinterpret_cast<float4*>(&w[0]) = *reinterpret_cast<const float4*>(&Ws[k][tx * 8]);
            *reinterpret_cast<float4*>(&w[4]) = *reinterpret_cast<const float4*>(&Ws[k][tx * 8 + 4]);
            #pragma unroll
            for (int i = 0; i < 8; ++i)
                #pragma unroll
                for (int j = 0; j < 8; ++j)
                    acc[i][j] = fmaf(a[i], w[j], acc[i][j]);
        }
        __syncthreads();
    }

    float bz[8];
    #pragma unroll
    for (int j = 0; j < 8; ++j) bz[j] = BIAS ? bias[tx * 8 + j] : 0.0f;

    #pragma unroll
    for (int i = 0; i < 8; ++i) {
        int gr = r0 + ty * 8 + i;
        if (gr < M) {
            float* o = out + (size_t)gr * BN + tx * 8;
            #pragma unroll
            for (int j4 = 0; j4 < 8; j4 += 4) {
                float4 v;
                v.x = acc[i][j4 + 0] + bz[j4 + 0];
                v.y = acc[i][j4 + 1] + bz[j4 + 1];
                v.z = acc[i][j4 + 2] + bz[j4 + 2];
                v.w = acc[i][j4 + 3] + bz[j4 + 3];
                if (RELU) {
                    v.x = fmaxf(v.x, 0.0f); v.y = fmaxf(v.y, 0.0f);
                    v.z = fmaxf(v.z, 0.0f); v.w = fmaxf(v.w, 0.0f);
                }
                *reinterpret_cast<float4*>(o + j4) = v;
            }
        }
    }
}

// ---------------------------------------------------------------------------
// One wave per dst node. lane = (edge_slot = lane>>4, float4_chunk = lane&15).
// z (in-place) = mean(hsrc[src]) * z
__global__ __launch_bounds__(256) void agg_mul(const float* __restrict__ hsrc,
                                               const int* __restrict__ offs,
                                               const int* __restrict__ sorted,
                                               float* __restrict__ z, int ndst) {
    int wid = threadIdx.x >> 6;
    int lane = threadIdx.x & 63;
    int d = blockIdx.x * 4 + wid;
    if (d >= ndst) return;
    int start = offs[d];
    int end = offs[d + 1];
    int sub = lane >> 4;
    int fq = lane & 15;
    float4 acc = make_float4(0.f, 0.f, 0.f, 0.f);
    for (int e = start + sub; e < end; e += 4) {
        int sidx = sorted[e];
        float4 v = *reinterpret_cast<const float4*>(hsrc + (size_t)sidx * 64 + fq * 4);
        acc.x += v.x; acc.y += v.y; acc.z += v.z; acc.w += v.w;
    }
    #pragma unroll
    for (int o = 16; o <= 32; o <<= 1) {
        acc.x += __shfl_xor(acc.x, o, 64);
        acc.y += __shfl_xor(acc.y, o, 64);
        acc.z += __shfl_xor(acc.z, o, 64);
        acc.w += __shfl_xor(acc.w, o, 64);
    }
    if (sub == 0) {
        int cnt = end - start;
        float inv = (cnt > 0) ? (1.0f / (float)cnt) : 0.0f;
        size_t idx = (size_t)d * 64 + fq * 4;
        float4 hd = *reinterpret_cast<const float4*>(z + idx);
        float4 r;
        r.x = acc.x * inv * hd.x; r.y = acc.y * inv * hd.y;
        r.z = acc.z * inv * hd.z; r.w = acc.w * inv * hd.w;
        *reinterpret_cast<float4*>(z + idx) = r;
    }
}

// ---------------------------------------------------------------------------
extern "C" void kernel_launch(void* const* d_in, const int* in_sizes, int n_in,
                              void* d_out, int out_size, void* d_ws, size_t ws_size,
                              hipStream_t stream) {
    const float* x     = (const float*)d_in[0];
    const float* Wsrc1 = (const float*)d_in[1];
    const float* Wdst1 = (const float*)d_in[2];
    const float* Wout1 = (const float*)d_in[3];
    const float* b1    = (const float*)d_in[4];
    const float* Wsrc2 = (const float*)d_in[5];
    const float* Wdst2 = (const float*)d_in[6];
    const float* Wout2 = (const float*)d_in[7];
    const float* b2    = (const float*)d_in[8];
    const int* src1    = (const int*)d_in[9];
    const int* dst1    = (const int*)d_in[10];
    const int* src2    = (const int*)d_in[11];
    const int* dst2    = (const int*)d_in[12];
    float* out = (float*)d_out;

    // workspace layout
    float* f = (float*)d_ws;
    float* hsrc1 = f;                          // N0*64 (reused as hsrc2)
    float* hdst1 = hsrc1 + (size_t)N0 * 64;    // N1*64 (becomes z1 in-place)
    float* h     = hdst1 + (size_t)N1 * 64;    // N1*128
    float* hdst2 = h + (size_t)N1 * 128;       // N2*64 (becomes z2 in-place)
    int* ip = (int*)(hdst2 + (size_t)N2 * 64);
    int* cur1    = ip; ip += N1;               // cur1,cur2 contiguous for fused zero
    int* cur2    = ip; ip += N2;
    int* offs1   = ip; ip += N1 + 4;
    int* offs2   = ip; ip += N2 + 4;
    int* sorted1 = ip; ip += E1C;
    int* sorted2 = ip; ip += E2C;
    int* part1   = ip; ip += 52;
    int* part2   = ip; ip += 12;

    const int B1 = (N1 + 1023) / 1024;   // 49
    const int B2 = (N2 + 1023) / 1024;   // 10

    // --- CSR build for both layers ---
    zero_ints<<<(N1 + N2 + 255) / 256, 256, 0, stream>>>(cur1, N1 + N2);
    hist_dual<<<(E1C + E2C + 255) / 256, 256, 0, stream>>>(dst1, cur1, E1C, dst2, cur2, E2C);
    scan_partial_dual<<<B1 + B2, 256, 0, stream>>>(cur1, N1, part1, B1, cur2, N2, part2);
    scan_mid<<<1, 64, 0, stream>>>(part1, B1, part2, B2);
    scan_final_dual<<<B1 + B2, 256, 0, stream>>>(cur1, offs1, N1, E1C, part1, B1,
                                                 cur2, offs2, N2, E2C, part2);
    scatter_dual<<<(E1C + E2C + 255) / 256, 256, 0, stream>>>(dst1, src1, cur1, sorted1, E1C,
                                                              dst2, src2, cur2, sorted2, E2C);

    // --- layer 1 ---
    gemm_tiled<128, 256, 64, false, false><<<(N0 + 255) / 256, 256, 0, stream>>>(x, Wsrc1, nullptr, hsrc1, N0);
    gemm_tiled<128, 256, 64, false, false><<<(N1 + 255) / 256, 256, 0, stream>>>(x, Wdst1, nullptr, hdst1, N1);
    agg_mul<<<(N1 + 3) / 4, 256, 0, stream>>>(hsrc1, offs1, sorted1, hdst1, N1);
    gemm_tiled<64, 128, 128, true, true><<<(N1 + 127) / 128, 256, 0, stream>>>(hdst1, Wout1, b1, h, N1);

    // --- layer 2 (hsrc1 buffer reused as hsrc2) ---
    gemm_tiled<128, 256, 64, false, false><<<(N1 + 255) / 256, 256, 0, stream>>>(h, Wsrc2, nullptr, hsrc1, N1);
    gemm_tiled<128, 128, 64, false, false><<<(N2 + 127) / 128, 128, 0, stream>>>(h, Wdst2, nullptr, hdst2, N2);
    agg_mul<<<(N2 + 3) / 4, 256, 0, stream>>>(hsrc1, offs2, sorted2, hdst2, N2);
    gemm_tiled<64, 128, 64, false, true><<<(N2 + 127) / 128, 128, 0, stream>>>(hdst2, Wout2, b2, out, N2);
}